// Round 15
// baseline (971.606 us; speedup 1.0000x reference)
//
#include <hip/hip_runtime.h>
#include <cstdint>
#include <cstddef>

#ifndef M_PI
#define M_PI 3.14159265358979323846
#endif

#define SRATE   16000
#define HOP     256
#define NFFT    2048
#define NBINS   1025
#define NMELS   80
#define BATCH   16
#define TLEN    131072
#define NF      513                 // frames
#define LOLA    133120              // NFFT + HOP*(NF-1)
#define FRAMEL  512
#define MINP    32
#define NLAGS   224                 // lags 32..255
#define NELEM   (BATCH*NBINS*NF)    // 8,413,200
#define MLPR    8                   // rows per k_mlp block (8208 = 8*1026)
#define DF      7.8125f             // (SRATE/2)/(NBINS-1), exact in f32

#define PADC(i) ((i) + ((i) >> 5))  // float2-LDS padding (1 elem per 32)

// ---------------- threefry2x32 (bit-exact vs jax) ----------------
__host__ __device__ inline void threefry2x32(uint32_t k0, uint32_t k1,
                                             uint32_t x0, uint32_t x1,
                                             uint32_t& o0, uint32_t& o1) {
  uint32_t ks0 = k0, ks1 = k1, ks2 = k0 ^ k1 ^ 0x1BD11BDAu;
  uint32_t ks[3] = {ks0, ks1, ks2};
  const uint32_t rot[2][4] = {{13u,15u,26u,6u},{17u,29u,16u,24u}};
  x0 += ks0; x1 += ks1;
#pragma unroll
  for (int i = 0; i < 5; ++i) {
#pragma unroll
    for (int r = 0; r < 4; ++r) {
      uint32_t rr = rot[i & 1][r];
      x0 += x1;
      x1 = (x1 << rr) | (x1 >> (32u - rr));
      x1 ^= x0;
    }
    x0 += ks[(i + 1) % 3];
    x1 += ks[(i + 2) % 3] + (uint32_t)(i + 1);
  }
  o0 = x0; o1 = x1;
}

__device__ inline float bits_to_uniform(uint32_t b) {
  uint32_t fb = (b >> 9) | 0x3f800000u;
  return __uint_as_float(fb) - 1.0f;    // [0,1), f32 like jax
}

// ---------------- register-blocked 1024-pt complex FFT (f32, float2 LDS) ----------------
// 128 threads x 8 complex f32. DIT radix-2; caller gathers bit-reversed.
// After P4, register m of thread t holds bin g = t + 128*m (natural order).
// Interleaved complex storage: one ds_read_b64/ds_write_b64 per element
// (bit-identical to split-array version; half the LDS instructions).
#define BF(e,o,WR,WI) do{ float vr=Xr[o]*(WR)-Xi[o]*(WI); \
  float vi=Xr[o]*(WI)+Xi[o]*(WR); float ur=Xr[e],ui=Xi[e]; \
  Xr[e]=ur+vr; Xi[e]=ui+vi; Xr[o]=ur-vr; Xi[o]=ui-vi; }while(0)

__device__ __forceinline__ void fft1024(float (&Xr)[8], float (&Xi)[8],
    float2* __restrict__ sc,
    const float* __restrict__ twr, const float* __restrict__ twi, float sgn)
{
  const int t = threadIdx.x;   // 0..127
  const float C7 = 0.70710678118654752440f;
  // ---- P1: g = 8t+m, h=1,2,4
  BF(0,1,1.0f,0.0f); BF(2,3,1.0f,0.0f); BF(4,5,1.0f,0.0f); BF(6,7,1.0f,0.0f);
  BF(0,2,1.0f,0.0f); BF(1,3,0.0f,sgn); BF(4,6,1.0f,0.0f); BF(5,7,0.0f,sgn);
  BF(0,4,1.0f,0.0f); BF(1,5,C7,sgn*C7); BF(2,6,0.0f,sgn); BF(3,7,-C7,sgn*C7);
  __syncthreads();                       // caller gathers done before overwrite
#pragma unroll
  for (int m = 0; m < 8; ++m) sc[PADC(8*t + m)] = make_float2(Xr[m], Xi[m]);
  __syncthreads();
  // ---- P2: g = f0 + 8m + 64f1, h=8,16,32
  {
    int f0 = t & 7, f1 = t >> 3;
#pragma unroll
    for (int m = 0; m < 8; ++m) { float2 v = sc[PADC(f0 + 8*m + 64*f1)]; Xr[m] = v.x; Xi[m] = v.y; }
    int x = 128*f0; float wr = twr[x], wi = sgn*twi[x];
    BF(0,1,wr,wi); BF(2,3,wr,wi); BF(4,5,wr,wi); BF(6,7,wr,wi);
    x = 64*f0;      float ar = twr[x], ai = sgn*twi[x];
    x = 64*(f0+8);  float br = twr[x], bi = sgn*twi[x];
    BF(0,2,ar,ai); BF(1,3,br,bi); BF(4,6,ar,ai); BF(5,7,br,bi);
#pragma unroll
    for (int mm = 0; mm < 4; ++mm) {
      x = 32*(f0 + 8*mm); float cr = twr[x], ci = sgn*twi[x];
      BF(mm, mm+4, cr, ci);
    }
#pragma unroll
    for (int m = 0; m < 8; ++m) sc[PADC(f0 + 8*m + 64*f1)] = make_float2(Xr[m], Xi[m]);
  }
  __syncthreads();
  // ---- P3: g = f0 + 64m + 512f1, h=64,128,256
  {
    int f0 = t & 63, f1 = t >> 6;
#pragma unroll
    for (int m = 0; m < 8; ++m) { float2 v = sc[PADC(f0 + 64*m + 512*f1)]; Xr[m] = v.x; Xi[m] = v.y; }
    int x = 16*f0; float wr = twr[x], wi = sgn*twi[x];
    BF(0,1,wr,wi); BF(2,3,wr,wi); BF(4,5,wr,wi); BF(6,7,wr,wi);
    x = 8*f0;       float ar = twr[x], ai = sgn*twi[x];
    x = 8*(f0+64);  float br = twr[x], bi = sgn*twi[x];
    BF(0,2,ar,ai); BF(1,3,br,bi); BF(4,6,ar,ai); BF(5,7,br,bi);
#pragma unroll
    for (int mm = 0; mm < 4; ++mm) {
      x = 4*(f0 + 64*mm); float cr = twr[x], ci = sgn*twi[x];
      BF(mm, mm+4, cr, ci);
    }
#pragma unroll
    for (int m = 0; m < 8; ++m) sc[PADC(f0 + 64*m + 512*f1)] = make_float2(Xr[m], Xi[m]);
  }
  __syncthreads();
  // ---- P4: g = t + 128m, h=512
  {
#pragma unroll
    for (int m = 0; m < 8; ++m) { float2 v = sc[PADC(t + 128*m)]; Xr[m] = v.x; Xi[m] = v.y; }
#pragma unroll
    for (int mm = 0; mm < 4; ++mm) {
      int x = 2*t + 256*mm; float cr = twr[x], ci = sgn*twi[x];
      BF(mm, mm+4, cr, ci);
    }
  }
}

// forward r2c epilogue (f32): registers hold Z[g=t+128m] of packed z[n]=x[2n]+ix[2n+1].
__device__ __forceinline__ void r2c_combine(float (&Xr)[8], float (&Xi)[8],
    float2* __restrict__ sc,
    const float* __restrict__ twr, const float* __restrict__ twi,
    float& x1024r)
{
  const int t = threadIdx.x;
  __syncthreads();                       // P4 reads done
#pragma unroll
  for (int m = 0; m < 8; ++m) sc[PADC(t + 128*m)] = make_float2(Xr[m], Xi[m]);
  __syncthreads();
  if (t == 0) x1024r = Xr[0] - Xi[0];
#pragma unroll
  for (int m = 0; m < 8; ++m) {
    int k  = t + 128*m;
    float2 zm = sc[PADC((1024 - k) & 1023)];
    float Er  = 0.5f*(Xr[m] + zm.x), Ei  = 0.5f*(Xi[m] - zm.y);
    float Odr = 0.5f*(Xr[m] - zm.x), Odi = 0.5f*(Xi[m] + zm.y);
    float Or  = Odi, Oi = -Odr;          // O = -i*(Z-conj(Zm))/2
    float wr  = twr[k], wi = -twi[k];    // W = e^{-i*2pi*k/2048}
    Xr[m] = Er + (wr*Or - wi*Oi);
    Xi[m] = Ei + (wr*Oi + wi*Or);
  }
}

// mel -> linear interp for one bin k from LDS f32 melrow (f32 math; src never
// within 1/410 of an integer so f32 rounding cannot flip i0)
__device__ inline float lin_interp_s(const float* __restrict__ melsh, int k) {
  float src = ((float)k + 0.5f) * ((float)NMELS / (float)NBINS) - 0.5f;
  src = src < 0.0f ? 0.0f : src;
  int i0 = (int)src; if (i0 > NMELS - 1) i0 = NMELS - 1;
  int i1 = i0 + 1 > NMELS - 1 ? NMELS - 1 : i0 + 1;
  float w = src - (float)i0;
  return (1.0f - w) * melsh[i0] + w * melsh[i1];
}

// ---------------- init A: paired window, win^2, f32 twiddles, f_pts, mel ranges ----------------
__global__ __launch_bounds__(256) void k_init_a(float2* __restrict__ winp,
                                                double* __restrict__ win2,
                                                float* __restrict__ twrf, float* __restrict__ twif,
                                                float* __restrict__ fptsf,
                                                int2* __restrict__ melrange) {
  int i = blockIdx.x * 256 + threadIdx.x;
  if (i < NFFT) {
    double w = 0.5 - 0.5 * cos(2.0 * M_PI * (double)i / (double)NFFT);
    win2[i] = w * w;
  }
  if (i < 1024) {
    double w0 = 0.5 - 0.5 * cos(2.0 * M_PI * (double)(2*i)   / (double)NFFT);
    double w1 = 0.5 - 0.5 * cos(2.0 * M_PI * (double)(2*i+1) / (double)NFFT);
    winp[i] = make_float2((float)w0, (float)w1);
    double th = 2.0 * M_PI * (double)i / (double)NFFT;
    twrf[i] = (float)cos(th); twif[i] = (float)sin(th);
  }
  if (i < NMELS + 2) {                   // f_pts[82], same formula/order as reference
    double m_max = 2595.0 * log10(1.0 + (SRATE / 2.0) / 700.0);
    fptsf[i] = (float)(700.0 * (pow(10.0, ((double)i * m_max / (double)(NMELS + 1)) / 2595.0) - 1.0));
  }
  if (i < NMELS) {                       // per-mel positive-weight bin range [lo,hi) — analytic
    double m_max = 2595.0 * log10(1.0 + (SRATE / 2.0) / 700.0);
    double fp0 = 700.0 * (pow(10.0, ((double)i       * m_max / (double)(NMELS + 1)) / 2595.0) - 1.0);
    double fp1 = 700.0 * (pow(10.0, ((double)(i + 1) * m_max / (double)(NMELS + 1)) / 2595.0) - 1.0);
    double fp2 = 700.0 * (pow(10.0, ((double)(i + 2) * m_max / (double)(NMELS + 1)) / 2595.0) - 1.0);
    int lo = (int)floor(fp0 / 7.8125) + 1;
    int hi = (int)ceil (fp2 / 7.8125);
    if (lo < 0) lo = 0; if (lo > NBINS) lo = NBINS;
    if (hi < 0) hi = 0; if (hi > NBINS) hi = NBINS;
    #define WGT(k) fmin(((double)(k)*7.8125 - fp0)/(fp1 - fp0), (fp2 - (double)(k)*7.8125)/(fp2 - fp1))
    while (lo > 0 && WGT(lo - 1) > 0.0) --lo;
    while (lo < hi && WGT(lo) <= 0.0) ++lo;
    while (hi < NBINS && WGT(hi) > 0.0) ++hi;
    while (hi > lo && WGT(hi - 1) <= 0.0) --hi;
    #undef WGT
    melrange[i] = make_int2(lo, hi);
  }
}

// ---------------- init B: envelope reciprocal ----------------
__global__ __launch_bounds__(256) void k_init_b(const double* __restrict__ win2,
                                                float* __restrict__ envif) {
  int i = blockIdx.x * 256 + threadIdx.x;
  if (i < LOLA) {
    int lo = i - (NFFT - 1);
    int fmin = lo <= 0 ? 0 : (lo + HOP - 1) / HOP;
    int fmax = i / HOP; if (fmax > NF - 1) fmax = NF - 1;
    double s = 0.0;
    for (int f = fmin; f <= fmax; ++f) s += win2[i - HOP * f];
    envif[i] = (float)(1.0 / (s > 1e-11 ? s : 1.0));
  }
}

// ---------------- random initial angles (jax partitionable threefry) ----------------
__global__ __launch_bounds__(256) void k_angles(float2* __restrict__ A,
                                                uint32_t kr0, uint32_t kr1,
                                                uint32_t ki0, uint32_t ki1) {
  uint32_t idx = blockIdx.x * 256u + threadIdx.x;
  if (idx >= (uint32_t)NELEM) return;
  uint32_t per_b = (uint32_t)(NF * NBINS);
  uint32_t b = idx / per_b, r = idx % per_b;
  uint32_t t = r / NBINS, k = r % NBINS;
  uint32_t j = (b * (uint32_t)NBINS + k) * (uint32_t)NF + t;
  uint32_t a0, a1, b0, b1;
  threefry2x32(kr0, kr1, 0u, j, a0, a1);   // real part bits
  threefry2x32(ki0, ki1, 0u, j, b0, b1);   // imag part bits
  A[idx] = make_float2(bits_to_uniform(a0 ^ a1), bits_to_uniform(b0 ^ b1));
}

// ---------------- STFT (real-packed, f32) + mel GATHER (no atomics) ----------------
__global__ __launch_bounds__(128) void k_stft_mel(const float* __restrict__ x,
                                                  const float2* __restrict__ winp,
                                                  const float* __restrict__ twrf, const float* __restrict__ twif,
                                                  const float* __restrict__ fptsf, const int2* __restrict__ melrange,
                                                  float* __restrict__ mel) {
  __shared__ float2 sc[1058];
  __shared__ float fsh[NMELS + 2];
  __shared__ int2  rsh[NMELS];
  int b = blockIdx.x / NF, tf = blockIdx.x % NF;
  int t = threadIdx.x;
  const float* xb = x + (size_t)b * TLEN;
  if (t < NMELS + 2) fsh[t] = fptsf[t];
  if (t < NMELS)     rsh[t] = melrange[t];
  if (tf >= 4 && tf <= 508) {            // interior: natural float2 loads
    const float2* xb2 = (const float2*)xb;
#pragma unroll
    for (int s = 0; s < 8; ++s) {
      int n = t + 128 * s;
      float2 v = xb2[128 * tf + n - 512];
      float2 w = winp[n];
      sc[PADC(n)] = make_float2(v.x * w.x, v.y * w.y);
    }
  } else {
#pragma unroll
    for (int s = 0; s < 8; ++s) {        // boundary: reflect scalar path
      int n = t + 128 * s;
      int j0 = HOP * tf + 2 * n - (NFFT / 2);
      int m0 = j0 < 0 ? -j0 : (j0 >= TLEN ? 2 * TLEN - 2 - j0 : j0);
      int j1 = j0 + 1;
      int m1 = j1 < 0 ? -j1 : (j1 >= TLEN ? 2 * TLEN - 2 - j1 : j1);
      float2 w = winp[n];
      sc[PADC(n)] = make_float2(xb[m0] * w.x, xb[m1] * w.y);
    }
  }
  __syncthreads();
  float Xr[8], Xi[8];
  int rt = (int)(__brev((unsigned)t) >> 25);
  const int r3[8] = {0,4,2,6,1,5,3,7};
#pragma unroll
  for (int m = 0; m < 8; ++m) {
    float2 v = sc[PADC(rt + 128 * r3[m])];
    Xr[m] = v.x; Xi[m] = v.y;
  }
  fft1024(Xr, Xi, sc, twrf, twif, -1.0f);
  float x1024r = 0.0f;
  r2c_combine(Xr, Xi, sc, twrf, twif, x1024r);
  __syncthreads();                        // combine reads done; reuse LDS for mag
  float* mag = (float*)sc;
#pragma unroll
  for (int m = 0; m < 8; ++m) {
    int k = t + 128 * m;
    mag[k] = sqrtf(Xr[m]*Xr[m] + Xi[m]*Xi[m]);
  }
  if (t == 0) mag[1024] = fabsf(x1024r);
  __syncthreads();
  if (t < NMELS) {                        // gather: one mel per thread
    float fp0 = fsh[t], fp1 = fsh[t + 1], fp2 = fsh[t + 2];
    float id0 = 1.0f / (fp1 - fp0), id1 = 1.0f / (fp2 - fp1);
    int2 r = rsh[t];
    float acc = 0.0f;
    for (int k = r.x; k < r.y; ++k) {
      float freq = (float)k * DF;
      float w = fminf((freq - fp0) * id0, (fp2 - freq) * id1);
      acc += mag[k] * fmaxf(w, 0.0f);
    }
    mel[(size_t)blockIdx.x * NMELS + t] = acc;
  }
}

// ---------------- iSTFT (c2r via packed 1024 iFFT, f32) -> windowed frame store ----------------
__global__ __launch_bounds__(128) void k_istft(const float* __restrict__ mel, const float2* __restrict__ A,
                                               const float2* __restrict__ winp,
                                               const float* __restrict__ twrf, const float* __restrict__ twif,
                                               float2* __restrict__ fr2) {
  __shared__ float2 sc[1058];
  __shared__ float melsh[NMELS];
  int t = threadIdx.x;
  size_t row = blockIdx.x;
  const float2* Arow = A + row * NBINS;
  if (t < NMELS) melsh[t] = mel[row * NMELS + t];
  __syncthreads();
#pragma unroll
  for (int s = 0; s < 9; ++s) {          // stage X[k]; zero imag at DC/Nyquist (c2r semantics)
    int k = t + 128 * s;
    if (k < NBINS) {
      float sv = lin_interp_s(melsh, k);
      float2 a = Arow[k];
      sc[PADC(k)] = make_float2(sv * a.x,
                                (k == 0 || k == 1024) ? 0.0f : sv * a.y);
    }
  }
  __syncthreads();
  float Xr[8], Xi[8];
  int rt = (int)(__brev((unsigned)t) >> 25);
  const int r3[8] = {0,4,2,6,1,5,3,7};
#pragma unroll
  for (int m = 0; m < 8; ++m) {          // Z[n] = E + i*O, gathered bit-reversed
    int n  = rt + 128 * r3[m];
    float2 vp = sc[PADC(n)], vq = sc[PADC(1024 - n)];
    float Er = 0.5f*(vp.x + vq.x), Ei = 0.5f*(vp.y - vq.y);
    float Fr = 0.5f*(vp.x - vq.x), Fi = 0.5f*(vp.y + vq.y);
    float wr = twrf[n], wi = twif[n];    // e^{+i*2pi*n/2048}
    float Or = wr*Fr - wi*Fi, Oi = wr*Fi + wi*Fr;
    Xr[m] = Er - Oi;
    Xi[m] = Ei + Or;
  }
  fft1024(Xr, Xi, sc, twrf, twif, +1.0f);
  float2* frrow = fr2 + row * 1024;
  const float invM = 1.0f / 1024.0f;
#pragma unroll
  for (int m = 0; m < 8; ++m) {          // z[g]: x[2g]=Re, x[2g+1]=Im; coalesced float2
    int g = t + 128 * m;
    float2 w = winp[g];
    frrow[g] = make_float2(Xr[m] * invM * w.x,
                           Xi[m] * invM * w.y);
  }
}

// ---------------- OLA gather + normalize, 4 samples/thread ----------------
__global__ __launch_bounds__(256) void k_ola(const float* __restrict__ fr,
                                             const float* __restrict__ envif,
                                             float* __restrict__ y, float* __restrict__ out) {
  size_t idx = (size_t)blockIdx.x * 256 + threadIdx.x;
  const size_t QROW = LOLA / 4;           // 33280 quads per batch row
  if (idx >= (size_t)BATCH * QROW) return;
  int b = (int)(idx / QROW);
  int i0 = 4 * (int)(idx % QROW);
  const float* frb = fr + (size_t)b * NF * NFFT;
  int lo0 = i0 - (NFFT - 1);
  int fm0 = lo0 <= 0 ? 0 : (lo0 + HOP - 1) / HOP;
  int fx0 = i0 / HOP; if (fx0 > NF - 1) fx0 = NF - 1;
  int i3 = i0 + 3;
  int lo3 = i3 - (NFFT - 1);
  int fm3 = lo3 <= 0 ? 0 : (lo3 + HOP - 1) / HOP;
  int fx3 = i3 / HOP; if (fx3 > NF - 1) fx3 = NF - 1;
  float4 v;
  if (fm0 == fm3 && fx0 == fx3) {         // uniform range: float4 fast path
    float4 s = make_float4(0.f, 0.f, 0.f, 0.f);
    for (int f = fm0; f <= fx0; ++f) {
      const float4 a = *(const float4*)(frb + (size_t)f * NFFT + (i0 - HOP * f));
      s.x += a.x; s.y += a.y; s.z += a.z; s.w += a.w;
    }
    const float4 e = *(const float4*)(envif + i0);
    v = make_float4(s.x * e.x, s.y * e.y, s.z * e.z, s.w * e.w);
  } else {                                // boundary quad: per-element
    float vv[4];
#pragma unroll
    for (int u = 0; u < 4; ++u) {
      int i = i0 + u;
      int lo = i - (NFFT - 1);
      int fmin = lo <= 0 ? 0 : (lo + HOP - 1) / HOP;
      int fmax = i / HOP; if (fmax > NF - 1) fmax = NF - 1;
      float s = 0.0f;
      for (int f = fmin; f <= fmax; ++f)
        s += frb[(size_t)f * NFFT + (i - HOP * f)];
      vv[u] = s * envif[i];
    }
    v = make_float4(vv[0], vv[1], vv[2], vv[3]);
  }
  if (out) {
    int j0 = i0 - NFFT / 2;               // 1024-aligned shift: j0 % 4 == 0
    if (j0 >= 0 && j0 + 3 < TLEN) {
      *(float4*)(out + (size_t)b * TLEN + j0) = v;
    } else {
      const float vv[4] = {v.x, v.y, v.z, v.w};
#pragma unroll
      for (int u = 0; u < 4; ++u) {
        int j = j0 + u;
        if (j >= 0 && j < TLEN) out[(size_t)b * TLEN + j] = vv[u];
      }
    }
  } else {
    *(float4*)(y + (size_t)b * LOLA + i0) = v;
  }
}

// ---------------- STFT of inv (real-packed, f32) + GL angle/momentum update ----------------
__global__ __launch_bounds__(128) void k_stft_gl(const float* __restrict__ y,
                                                 const float2* __restrict__ winp,
                                                 const float* __restrict__ twrf, const float* __restrict__ twif,
                                                 float2* __restrict__ A, float2* __restrict__ P, double mom) {
  __shared__ float2 sc[1058];
  int b = blockIdx.x / NF, tf = blockIdx.x % NF;
  int t = threadIdx.x;
  const float* yb = y + (size_t)b * LOLA;
  if (tf >= 4 && tf <= 508) {            // interior: y index = 256*tf + 2n -> float2
    const float2* yb2 = (const float2*)yb;
#pragma unroll
    for (int s = 0; s < 8; ++s) {
      int n = t + 128 * s;
      float2 v = yb2[128 * tf + n];
      float2 w = winp[n];
      sc[PADC(n)] = make_float2(v.x * w.x, v.y * w.y);
    }
  } else {
#pragma unroll
    for (int s = 0; s < 8; ++s) {
      int n = t + 128 * s;
      int j0 = HOP * tf + 2 * n - (NFFT / 2);
      int m0 = j0 < 0 ? -j0 : (j0 >= TLEN ? 2 * TLEN - 2 - j0 : j0);
      int j1 = j0 + 1;
      int m1 = j1 < 0 ? -j1 : (j1 >= TLEN ? 2 * TLEN - 2 - j1 : j1);
      float2 w = winp[n];
      sc[PADC(n)] = make_float2(yb[NFFT/2 + m0] * w.x, yb[NFFT/2 + m1] * w.y);
    }
  }
  __syncthreads();
  float Xr[8], Xi[8];
  int rt = (int)(__brev((unsigned)t) >> 25);
  const int r3[8] = {0,4,2,6,1,5,3,7};
#pragma unroll
  for (int m = 0; m < 8; ++m) {
    float2 v = sc[PADC(rt + 128 * r3[m])];
    Xr[m] = v.x; Xi[m] = v.y;
  }
  fft1024(Xr, Xi, sc, twrf, twif, -1.0f);
  float x1024r = 0.0f;
  r2c_combine(Xr, Xi, sc, twrf, twif, x1024r);
  size_t row = blockIdx.x;
  float2* Arow = A + row * NBINS;
  float2* Prow = P + row * NBINS;
#pragma unroll
  for (int m = 0; m < 8; ++m) {
    int k = t + 128 * m;
    double rr = (double)Xr[m], ri = (double)Xi[m];
    float2 p = Prow[k];
    double ar = rr - mom * (double)p.x, ai = ri - mom * (double)p.y;
    double mg = sqrt(ar * ar + ai * ai) + 1e-16;
    Arow[k] = make_float2((float)(ar / mg), (float)(ai / mg));
    Prow[k] = make_float2((float)rr, (float)ri);
  }
  if (t == 0) {                           // Nyquist bin (imag exactly 0)
    float2 p = Prow[1024];
    double ar = (double)x1024r - mom * (double)p.x, ai = -mom * (double)p.y;
    double mg = sqrt(ar * ar + ai * ai) + 1e-16;
    Arow[1024] = make_float2((float)(ar / mg), (float)(ai / mg));
    Prow[1024] = make_float2(x1024r, 0.0f);
  }
}

// ---------------- f0 + loudness (parity-split lags: conflict-free LDS) ----------------
__global__ __launch_bounds__(256) void k_feats(const float* __restrict__ x, double* __restrict__ feats) {
  __shared__ float xe[520], xo[520];      // xo[i] = xe[i+1]
  __shared__ double vals[256];
  __shared__ int vidx[256];
  int b = blockIdx.x / NF, tf = blockIdx.x % NF;
  const float* xb = x + (size_t)b * TLEN;
  int tid = threadIdx.x;
  for (int n = tid; n < FRAMEL; n += 256) {
    int j = HOP * tf + n - (FRAMEL / 2);
    int m = j < 0 ? -j : (j >= TLEN ? 2 * TLEN - 2 - j : j);
    xe[n] = xb[m];
  }
  if (tid < 8) xe[FRAMEL + tid] = 0.0f;
  __syncthreads();
  for (int n = tid; n < 519; n += 256) xo[n] = xe[n + 1];
  if (tid == 0) xo[519] = 0.0f;
  // loudness sum of squares (f64 accum of exact f32 values)
  double ss = 0.0;
  for (int n = tid; n < FRAMEL; n += 256) { double v = (double)xe[n]; ss += v * v; }
  vals[tid] = ss;
  __syncthreads();
  for (int w = 128; w > 0; w >>= 1) {
    if (tid < w) vals[tid] += vals[tid + w];
    __syncthreads();
  }
  double sumsq = vals[0];
  __syncthreads();
  int q   = (tid < 128) ? tid : tid - 128;
  int lag = (tid < 128) ? (32 + 2 * q) : (33 + 2 * q);
  bool active = q < 112;
  double acc = -1e300;
  if (active) {
    acc = 0.0;
    const float2* e2 = (const float2*)xe;
    const float2* s2 = (const float2*)((tid < 128) ? xe : xo);
    int kb = 16 + q;                      // lag>>1 for both parities
    for (int n0 = 0; n0 < FRAMEL - lag; n0 += 8) {
      int h = n0 >> 1;
      float2 a0 = e2[h],    a1 = e2[h+1],    a2 = e2[h+2],    a3 = e2[h+3];
      float2 b0 = s2[h+kb], b1 = s2[h+kb+1], b2 = s2[h+kb+2], b3 = s2[h+kb+3];
      acc += (double)a0.x * (double)b0.x; acc += (double)a0.y * (double)b0.y;
      acc += (double)a1.x * (double)b1.x; acc += (double)a1.y * (double)b1.y;
      acc += (double)a2.x * (double)b2.x; acc += (double)a2.y * (double)b2.y;
      acc += (double)a3.x * (double)b3.x; acc += (double)a3.y * (double)b3.y;
    }
  }
  vals[tid] = acc; vidx[tid] = lag;
  __syncthreads();
  for (int w = 128; w > 0; w >>= 1) {     // first-max argmax tree (lag-order tie-break)
    if (tid < w) {
      double vl = vals[tid], vr = vals[tid + w];
      int il = vidx[tid], ir = vidx[tid + w];
      if (vr > vl || (vr == vl && ir < il)) { vals[tid] = vr; vidx[tid] = ir; }
    }
    __syncthreads();
  }
  if (tid == 0) {
    double period = (double)vidx[0];
    double f0 = (double)SRATE / (period + 1e-8);
    f0 = f0 < 50.0 ? 50.0 : (f0 > 500.0 ? 500.0 : f0);
    double mean = sumsq / (double)FRAMEL;
    double loud = 20.0 * log10(sqrt(mean) + 1e-8);
    feats[(size_t)blockIdx.x * 2 + 0] = f0;
    feats[(size_t)blockIdx.x * 2 + 1] = loud;
  }
}

// ---------------- MLP 2->256->256->64 (elu), 8 rows/block ----------------
__global__ __launch_bounds__(256) void k_mlp(const double* __restrict__ feats,
                                             const float* __restrict__ W1, const float* __restrict__ b1,
                                             const float* __restrict__ W2, const float* __restrict__ b2,
                                             const float* __restrict__ W3, const float* __restrict__ b3,
                                             float* __restrict__ out) {
  __shared__ double h1[MLPR][256];
  __shared__ double h2[MLPR][256];
  __shared__ double fsh[MLPR][2];
  int j = threadIdx.x;
  size_t row0 = (size_t)blockIdx.x * MLPR;
  if (j < MLPR * 2) ((double*)fsh)[j] = feats[row0 * 2 + j];
  __syncthreads();
  double w1a = (double)W1[j], w1b = (double)W1[256 + j], bb1 = (double)b1[j];
#pragma unroll
  for (int r = 0; r < MLPR; ++r) {
    double v = fsh[r][0] * w1a + fsh[r][1] * w1b + bb1;
    h1[r][j] = v > 0.0 ? v : expm1(v);
  }
  __syncthreads();
  double acc[MLPR];
  double bb2 = (double)b2[j];
#pragma unroll
  for (int r = 0; r < MLPR; ++r) acc[r] = bb2;
  for (int i = 0; i < 256; ++i) {
    double w = (double)W2[i * 256 + j];
#pragma unroll
    for (int r = 0; r < MLPR; ++r) acc[r] += h1[r][i] * w;
  }
#pragma unroll
  for (int r = 0; r < MLPR; ++r) h2[r][j] = acc[r] > 0.0 ? acc[r] : expm1(acc[r]);
  __syncthreads();
  int o = j & 63, rg = j >> 6;            // 4 row-pairs across 256 threads
  int r0 = rg * 2, r1 = r0 + 1;
  double o0 = (double)b3[o], o1 = o0;
  for (int i = 0; i < 256; ++i) {
    double w = (double)W3[i * 64 + o];
    o0 += h2[r0][i] * w;
    o1 += h2[r1][i] * w;
  }
  out[(row0 + r0) * 64 + o] = (float)o0;
  out[(row0 + r1) * 64 + o] = (float)o1;
}

// sentinel: marks "workspace too small" path unambiguously
__global__ void k_sentinel(float* out) { out[0] = 31337.0f; }

// ---------------- host ----------------
extern "C" void kernel_launch(void* const* d_in, const int* in_sizes, int n_in,
                              void* d_out, int out_size, void* d_ws, size_t ws_size,
                              hipStream_t stream) {
  const float* x  = (const float*)d_in[0];
  const float* W1 = (const float*)d_in[1];
  const float* b1 = (const float*)d_in[2];
  const float* W2 = (const float*)d_in[3];
  const float* b2 = (const float*)d_in[4];
  const float* W3 = (const float*)d_in[5];
  const float* b3 = (const float*)d_in[6];
  float* out = (float*)d_out;

  // f64 region
  double* ws = (double*)d_ws;
  size_t o = 0;
  double*  winsq = ws + o; o += NFFT;
  double*  feats = ws + o; o += (size_t)BATCH * NF * 2;
  // f32 region (8B aligned: o doubles consumed)
  float2* winp  = (float2*)(ws + o);                         // 1024 float2
  float*  twrf  = (float*)(winp + 1024);                     // 1024
  float*  twif  = twrf + 1024;                               // 1024
  float*  fptsf = twif + 1024;                               // 84 (pad to even)
  int2*   melrange = (int2*)(fptsf + 84);                    // 80 int2 (8B aligned)
  float*  mel   = (float*)(melrange + NMELS);                // B*NF*80
  float*  fr    = mel + (size_t)BATCH * NF * NMELS;          // B*NF*2048 windowed frames (16B-aligned rows)
  float*  y     = fr + (size_t)BATCH * NF * NFFT;            // B*LOLA normalized inv
  float*  envif = y + (size_t)BATCH * LOLA;                  // LOLA
  float2* A     = (float2*)(envif + LOLA);
  float2* P     = A + (size_t)NELEM;
  size_t total_bytes = (size_t)((char*)(P + (size_t)NELEM) - (char*)d_ws);  // ~215 MiB

  if (ws_size < total_bytes) {           // diagnostic path: out[0] = 31337
    k_sentinel<<<1, 1, 0, stream>>>(out);
    return;
  }

  // jax.random.key(42) -> (0,42). Partitionable split: keys[i] = threefry(key, (0, i)).
  uint32_t kr0, kr1, ki0, ki1;
  threefry2x32(0u, 42u, 0u, 0u, kr0, kr1);   // kr = keys[0]
  threefry2x32(0u, 42u, 0u, 1u, ki0, ki1);   // ki = keys[1]

  const int NBLK = BATCH * NF;    // 8208
  const int OLAB = ((size_t)BATCH * (LOLA / 4) + 255) / 256;   // 4 samples/thread
  k_init_a<<<8, 256, 0, stream>>>(winp, winsq, twrf, twif, fptsf, melrange);
  k_init_b<<<(LOLA + 255) / 256, 256, 0, stream>>>(winsq, envif);
  k_stft_mel<<<NBLK, 128, 0, stream>>>(x, winp, twrf, twif, fptsf, melrange, mel);
  k_angles<<<(NELEM + 255) / 256, 256, 0, stream>>>(A, kr0, kr1, ki0, ki1);
  // No P memset: first GL iteration uses mom=0, so P's initial contents are
  // multiplied by 0.0 (poison bytes 0xAA = finite float -> exact no-op).

  const double mom = 0.99 / 1.99;
  for (int it = 0; it < 4; ++it) {
    k_istft<<<NBLK, 128, 0, stream>>>(mel, A, winp, twrf, twif, (float2*)fr);
    k_ola<<<OLAB, 256, 0, stream>>>(fr, envif, y, nullptr);
    k_stft_gl<<<NBLK, 128, 0, stream>>>(y, winp, twrf, twif, A, P, it == 0 ? 0.0 : mom);
  }
  k_istft<<<NBLK, 128, 0, stream>>>(mel, A, winp, twrf, twif, (float2*)fr);
  k_ola<<<OLAB, 256, 0, stream>>>(fr, envif, y, out);

  k_feats<<<NBLK, 256, 0, stream>>>(x, feats);
  k_mlp<<<NBLK / MLPR, 256, 0, stream>>>(feats, W1, b1, W2, b2, W3, b3, out + (size_t)BATCH * TLEN);
}

// Round 16
// 932.595 us; speedup vs baseline: 1.0418x; 1.0418x over previous
//
#include <hip/hip_runtime.h>
#include <cstdint>
#include <cstddef>

#ifndef M_PI
#define M_PI 3.14159265358979323846
#endif

#define SRATE   16000
#define HOP     256
#define NFFT    2048
#define NBINS   1025
#define NMELS   80
#define BATCH   16
#define TLEN    131072
#define NF      513                 // frames
#define LOLA    133120              // NFFT + HOP*(NF-1)
#define FRAMEL  512
#define MINP    32
#define NLAGS   224                 // lags 32..255
#define NELEM   (BATCH*NBINS*NF)    // 8,413,200
#define MLPR    8                   // rows per k_mlp block (8208 = 8*1026)
#define DF      7.8125f             // (SRATE/2)/(NBINS-1), exact in f32

#define PADF(i) ((i) + 3*((i) >> 5))  // f32-LDS padding: all FFT patterns <=2-way

// ---------------- threefry2x32 (bit-exact vs jax) ----------------
__host__ __device__ inline void threefry2x32(uint32_t k0, uint32_t k1,
                                             uint32_t x0, uint32_t x1,
                                             uint32_t& o0, uint32_t& o1) {
  uint32_t ks0 = k0, ks1 = k1, ks2 = k0 ^ k1 ^ 0x1BD11BDAu;
  uint32_t ks[3] = {ks0, ks1, ks2};
  const uint32_t rot[2][4] = {{13u,15u,26u,6u},{17u,29u,16u,24u}};
  x0 += ks0; x1 += ks1;
#pragma unroll
  for (int i = 0; i < 5; ++i) {
#pragma unroll
    for (int r = 0; r < 4; ++r) {
      uint32_t rr = rot[i & 1][r];
      x0 += x1;
      x1 = (x1 << rr) | (x1 >> (32u - rr));
      x1 ^= x0;
    }
    x0 += ks[(i + 1) % 3];
    x1 += ks[(i + 2) % 3] + (uint32_t)(i + 1);
  }
  o0 = x0; o1 = x1;
}

__device__ inline float bits_to_uniform(uint32_t b) {
  uint32_t fb = (b >> 9) | 0x3f800000u;
  return __uint_as_float(fb) - 1.0f;    // [0,1), f32 like jax
}

// ---------------- register-blocked 1024-pt complex FFT (f32) ----------------
// 128 threads x 8 complex f32. DIT radix-2; caller gathers bit-reversed.
// After P4, register m of thread t holds bin g = t + 128*m (natural order).
#define BF(e,o,WR,WI) do{ float vr=Xr[o]*(WR)-Xi[o]*(WI); \
  float vi=Xr[o]*(WI)+Xi[o]*(WR); float ur=Xr[e],ui=Xi[e]; \
  Xr[e]=ur+vr; Xi[e]=ui+vi; Xr[o]=ur-vr; Xi[o]=ui-vi; }while(0)

__device__ __forceinline__ void fft1024(float (&Xr)[8], float (&Xi)[8],
    float* __restrict__ sre, float* __restrict__ sim,
    const float* __restrict__ twr, const float* __restrict__ twi, float sgn)
{
  const int t = threadIdx.x;   // 0..127
  const float C7 = 0.70710678118654752440f;
  // ---- P1: g = 8t+m, h=1,2,4
  BF(0,1,1.0f,0.0f); BF(2,3,1.0f,0.0f); BF(4,5,1.0f,0.0f); BF(6,7,1.0f,0.0f);
  BF(0,2,1.0f,0.0f); BF(1,3,0.0f,sgn); BF(4,6,1.0f,0.0f); BF(5,7,0.0f,sgn);
  BF(0,4,1.0f,0.0f); BF(1,5,C7,sgn*C7); BF(2,6,0.0f,sgn); BF(3,7,-C7,sgn*C7);
  __syncthreads();
#pragma unroll
  for (int m = 0; m < 8; ++m) { int p = PADF(8*t + m); sre[p] = Xr[m]; sim[p] = Xi[m]; }
  __syncthreads();
  // ---- P2: g = f0 + 8m + 64f1, h=8,16,32
  {
    int f0 = t & 7, f1 = t >> 3;
#pragma unroll
    for (int m = 0; m < 8; ++m) { int p = PADF(f0 + 8*m + 64*f1); Xr[m] = sre[p]; Xi[m] = sim[p]; }
    int x = 128*f0; float wr = twr[x], wi = sgn*twi[x];
    BF(0,1,wr,wi); BF(2,3,wr,wi); BF(4,5,wr,wi); BF(6,7,wr,wi);
    x = 64*f0;      float ar = twr[x], ai = sgn*twi[x];
    x = 64*(f0+8);  float br = twr[x], bi = sgn*twi[x];
    BF(0,2,ar,ai); BF(1,3,br,bi); BF(4,6,ar,ai); BF(5,7,br,bi);
#pragma unroll
    for (int mm = 0; mm < 4; ++mm) {
      x = 32*(f0 + 8*mm); float cr = twr[x], ci = sgn*twi[x];
      BF(mm, mm+4, cr, ci);
    }
#pragma unroll
    for (int m = 0; m < 8; ++m) { int p = PADF(f0 + 8*m + 64*f1); sre[p] = Xr[m]; sim[p] = Xi[m]; }
  }
  __syncthreads();
  // ---- P3: g = f0 + 64m + 512f1, h=64,128,256
  {
    int f0 = t & 63, f1 = t >> 6;
#pragma unroll
    for (int m = 0; m < 8; ++m) { int p = PADF(f0 + 64*m + 512*f1); Xr[m] = sre[p]; Xi[m] = sim[p]; }
    int x = 16*f0; float wr = twr[x], wi = sgn*twi[x];
    BF(0,1,wr,wi); BF(2,3,wr,wi); BF(4,5,wr,wi); BF(6,7,wr,wi);
    x = 8*f0;       float ar = twr[x], ai = sgn*twi[x];
    x = 8*(f0+64);  float br = twr[x], bi = sgn*twi[x];
    BF(0,2,ar,ai); BF(1,3,br,bi); BF(4,6,ar,ai); BF(5,7,br,bi);
#pragma unroll
    for (int mm = 0; mm < 4; ++mm) {
      x = 4*(f0 + 64*mm); float cr = twr[x], ci = sgn*twi[x];
      BF(mm, mm+4, cr, ci);
    }
#pragma unroll
    for (int m = 0; m < 8; ++m) { int p = PADF(f0 + 64*m + 512*f1); sre[p] = Xr[m]; sim[p] = Xi[m]; }
  }
  __syncthreads();
  // ---- P4: g = t + 128m, h=512
  {
#pragma unroll
    for (int m = 0; m < 8; ++m) { int p = PADF(t + 128*m); Xr[m] = sre[p]; Xi[m] = sim[p]; }
#pragma unroll
    for (int mm = 0; mm < 4; ++mm) {
      int x = 2*t + 256*mm; float cr = twr[x], ci = sgn*twi[x];
      BF(mm, mm+4, cr, ci);
    }
  }
}

// forward r2c epilogue (f32): registers hold Z[g=t+128m] of packed z[n]=x[2n]+ix[2n+1].
__device__ __forceinline__ void r2c_combine(float (&Xr)[8], float (&Xi)[8],
    float* __restrict__ sre, float* __restrict__ sim,
    const float* __restrict__ twr, const float* __restrict__ twi,
    float& x1024r)
{
  const int t = threadIdx.x;
  __syncthreads();
#pragma unroll
  for (int m = 0; m < 8; ++m) { int p = PADF(t + 128*m); sre[p] = Xr[m]; sim[p] = Xi[m]; }
  __syncthreads();
  if (t == 0) x1024r = Xr[0] - Xi[0];
#pragma unroll
  for (int m = 0; m < 8; ++m) {
    int k  = t + 128*m;
    int km = PADF((1024 - k) & 1023);
    float zmr = sre[km], zmi = sim[km];
    float Er  = 0.5f*(Xr[m] + zmr), Ei  = 0.5f*(Xi[m] - zmi);
    float Odr = 0.5f*(Xr[m] - zmr), Odi = 0.5f*(Xi[m] + zmi);
    float Or  = Odi, Oi = -Odr;          // O = -i*(Z-conj(Zm))/2
    float wr  = twr[k], wi = -twi[k];    // W = e^{-i*2pi*k/2048}
    Xr[m] = Er + (wr*Or - wi*Oi);
    Xi[m] = Ei + (wr*Oi + wi*Or);
  }
}

// mel -> linear interp for one bin k from LDS f32 melrow (f32 math; src never
// within 1/410 of an integer so f32 rounding cannot flip i0)
__device__ inline float lin_interp_s(const float* __restrict__ melsh, int k) {
  float src = ((float)k + 0.5f) * ((float)NMELS / (float)NBINS) - 0.5f;
  src = src < 0.0f ? 0.0f : src;
  int i0 = (int)src; if (i0 > NMELS - 1) i0 = NMELS - 1;
  int i1 = i0 + 1 > NMELS - 1 ? NMELS - 1 : i0 + 1;
  float w = src - (float)i0;
  return (1.0f - w) * melsh[i0] + w * melsh[i1];
}

// ---------------- init A: paired window, win^2, f32 twiddles, f_pts, mel ranges ----------------
__global__ __launch_bounds__(256) void k_init_a(float2* __restrict__ winp,
                                                double* __restrict__ win2,
                                                float* __restrict__ twrf, float* __restrict__ twif,
                                                float* __restrict__ fptsf,
                                                int2* __restrict__ melrange) {
  int i = blockIdx.x * 256 + threadIdx.x;
  if (i < NFFT) {
    double w = 0.5 - 0.5 * cos(2.0 * M_PI * (double)i / (double)NFFT);
    win2[i] = w * w;
  }
  if (i < 1024) {
    double w0 = 0.5 - 0.5 * cos(2.0 * M_PI * (double)(2*i)   / (double)NFFT);
    double w1 = 0.5 - 0.5 * cos(2.0 * M_PI * (double)(2*i+1) / (double)NFFT);
    winp[i] = make_float2((float)w0, (float)w1);
    double th = 2.0 * M_PI * (double)i / (double)NFFT;
    twrf[i] = (float)cos(th); twif[i] = (float)sin(th);
  }
  if (i < NMELS + 2) {                   // f_pts[82], same formula/order as reference
    double m_max = 2595.0 * log10(1.0 + (SRATE / 2.0) / 700.0);
    fptsf[i] = (float)(700.0 * (pow(10.0, ((double)i * m_max / (double)(NMELS + 1)) / 2595.0) - 1.0));
  }
  if (i < NMELS) {                       // per-mel positive-weight bin range [lo,hi) — analytic
    double m_max = 2595.0 * log10(1.0 + (SRATE / 2.0) / 700.0);
    double fp0 = 700.0 * (pow(10.0, ((double)i       * m_max / (double)(NMELS + 1)) / 2595.0) - 1.0);
    double fp1 = 700.0 * (pow(10.0, ((double)(i + 1) * m_max / (double)(NMELS + 1)) / 2595.0) - 1.0);
    double fp2 = 700.0 * (pow(10.0, ((double)(i + 2) * m_max / (double)(NMELS + 1)) / 2595.0) - 1.0);
    int lo = (int)floor(fp0 / 7.8125) + 1;
    int hi = (int)ceil (fp2 / 7.8125);
    if (lo < 0) lo = 0; if (lo > NBINS) lo = NBINS;
    if (hi < 0) hi = 0; if (hi > NBINS) hi = NBINS;
    #define WGT(k) fmin(((double)(k)*7.8125 - fp0)/(fp1 - fp0), (fp2 - (double)(k)*7.8125)/(fp2 - fp1))
    while (lo > 0 && WGT(lo - 1) > 0.0) --lo;
    while (lo < hi && WGT(lo) <= 0.0) ++lo;
    while (hi < NBINS && WGT(hi) > 0.0) ++hi;
    while (hi > lo && WGT(hi - 1) <= 0.0) --hi;
    #undef WGT
    melrange[i] = make_int2(lo, hi);
  }
}

// ---------------- init B: envelope reciprocal ----------------
__global__ __launch_bounds__(256) void k_init_b(const double* __restrict__ win2,
                                                float* __restrict__ envif) {
  int i = blockIdx.x * 256 + threadIdx.x;
  if (i < LOLA) {
    int lo = i - (NFFT - 1);
    int fmin = lo <= 0 ? 0 : (lo + HOP - 1) / HOP;
    int fmax = i / HOP; if (fmax > NF - 1) fmax = NF - 1;
    double s = 0.0;
    for (int f = fmin; f <= fmax; ++f) s += win2[i - HOP * f];
    envif[i] = (float)(1.0 / (s > 1e-11 ? s : 1.0));
  }
}

// ---------------- random initial angles (jax partitionable threefry) ----------------
__global__ __launch_bounds__(256) void k_angles(float2* __restrict__ A,
                                                uint32_t kr0, uint32_t kr1,
                                                uint32_t ki0, uint32_t ki1) {
  uint32_t idx = blockIdx.x * 256u + threadIdx.x;
  if (idx >= (uint32_t)NELEM) return;
  uint32_t per_b = (uint32_t)(NF * NBINS);
  uint32_t b = idx / per_b, r = idx % per_b;
  uint32_t t = r / NBINS, k = r % NBINS;
  uint32_t j = (b * (uint32_t)NBINS + k) * (uint32_t)NF + t;
  uint32_t a0, a1, b0, b1;
  threefry2x32(kr0, kr1, 0u, j, a0, a1);   // real part bits
  threefry2x32(ki0, ki1, 0u, j, b0, b1);   // imag part bits
  A[idx] = make_float2(bits_to_uniform(a0 ^ a1), bits_to_uniform(b0 ^ b1));
}

// ---------------- STFT (real-packed, f32) + mel GATHER (no atomics) ----------------
__global__ __launch_bounds__(128) void k_stft_mel(const float* __restrict__ x,
                                                  const float2* __restrict__ winp,
                                                  const float* __restrict__ twrf, const float* __restrict__ twif,
                                                  const float* __restrict__ fptsf, const int2* __restrict__ melrange,
                                                  float* __restrict__ mel) {
  __shared__ float sre[1160], sim[1160];
  __shared__ float fsh[NMELS + 2];
  __shared__ int2  rsh[NMELS];
  int b = blockIdx.x / NF, tf = blockIdx.x % NF;
  int t = threadIdx.x;
  const float* xb = x + (size_t)b * TLEN;
  if (t < NMELS + 2) fsh[t] = fptsf[t];
  if (t < NMELS)     rsh[t] = melrange[t];
  if (tf >= 4 && tf <= 508) {            // interior: natural float2 loads
    const float2* xb2 = (const float2*)xb;
#pragma unroll
    for (int s = 0; s < 8; ++s) {
      int n = t + 128 * s;
      float2 v = xb2[128 * tf + n - 512];
      float2 w = winp[n];
      sre[PADF(n)] = v.x * w.x;
      sim[PADF(n)] = v.y * w.y;
    }
  } else {
#pragma unroll
    for (int s = 0; s < 8; ++s) {        // boundary: reflect scalar path
      int n = t + 128 * s;
      int j0 = HOP * tf + 2 * n - (NFFT / 2);
      int m0 = j0 < 0 ? -j0 : (j0 >= TLEN ? 2 * TLEN - 2 - j0 : j0);
      int j1 = j0 + 1;
      int m1 = j1 < 0 ? -j1 : (j1 >= TLEN ? 2 * TLEN - 2 - j1 : j1);
      float2 w = winp[n];
      sre[PADF(n)] = xb[m0] * w.x;
      sim[PADF(n)] = xb[m1] * w.y;
    }
  }
  __syncthreads();
  float Xr[8], Xi[8];
  int rt = (int)(__brev((unsigned)t) >> 25);
  const int r3[8] = {0,4,2,6,1,5,3,7};
#pragma unroll
  for (int m = 0; m < 8; ++m) {
    int p = PADF(rt + 128 * r3[m]);
    Xr[m] = sre[p]; Xi[m] = sim[p];
  }
  fft1024(Xr, Xi, sre, sim, twrf, twif, -1.0f);
  float x1024r = 0.0f;
  r2c_combine(Xr, Xi, sre, sim, twrf, twif, x1024r);
  __syncthreads();
#pragma unroll
  for (int m = 0; m < 8; ++m) {
    int k = t + 128 * m;
    sre[k] = sqrtf(Xr[m]*Xr[m] + Xi[m]*Xi[m]);
  }
  if (t == 0) sre[1024] = fabsf(x1024r);
  __syncthreads();
  if (t < NMELS) {                        // gather: one mel per thread
    float fp0 = fsh[t], fp1 = fsh[t + 1], fp2 = fsh[t + 2];
    float id0 = 1.0f / (fp1 - fp0), id1 = 1.0f / (fp2 - fp1);
    int2 r = rsh[t];
    float acc = 0.0f;
    for (int k = r.x; k < r.y; ++k) {
      float freq = (float)k * DF;
      float w = fminf((freq - fp0) * id0, (fp2 - freq) * id1);
      acc += sre[k] * fmaxf(w, 0.0f);
    }
    mel[(size_t)blockIdx.x * NMELS + t] = acc;
  }
}

// ---------------- iSTFT (c2r via packed 1024 iFFT, f32) -> windowed frame store ----------------
__global__ __launch_bounds__(128) void k_istft(const float* __restrict__ mel, const float2* __restrict__ A,
                                               const float2* __restrict__ winp,
                                               const float* __restrict__ twrf, const float* __restrict__ twif,
                                               float2* __restrict__ fr2) {
  __shared__ float sre[1160], sim[1160];
  __shared__ float melsh[NMELS];
  int t = threadIdx.x;
  size_t row = blockIdx.x;
  const float2* Arow = A + row * NBINS;
  if (t < NMELS) melsh[t] = mel[row * NMELS + t];
  __syncthreads();
#pragma unroll
  for (int s = 0; s < 9; ++s) {          // stage X[k]; zero imag at DC/Nyquist (c2r semantics)
    int k = t + 128 * s;
    if (k < NBINS) {
      float sv = lin_interp_s(melsh, k);
      float2 a = Arow[k];
      sre[PADF(k)] = sv * a.x;
      sim[PADF(k)] = (k == 0 || k == 1024) ? 0.0f : sv * a.y;
    }
  }
  __syncthreads();
  float Xr[8], Xi[8];
  int rt = (int)(__brev((unsigned)t) >> 25);
  const int r3[8] = {0,4,2,6,1,5,3,7};
#pragma unroll
  for (int m = 0; m < 8; ++m) {          // Z[n] = E + i*O, gathered bit-reversed
    int n  = rt + 128 * r3[m];
    int p  = PADF(n), q = PADF(1024 - n);
    float Er = 0.5f*(sre[p] + sre[q]), Ei = 0.5f*(sim[p] - sim[q]);
    float Fr = 0.5f*(sre[p] - sre[q]), Fi = 0.5f*(sim[p] + sim[q]);
    float wr = twrf[n], wi = twif[n];    // e^{+i*2pi*n/2048}
    float Or = wr*Fr - wi*Fi, Oi = wr*Fi + wi*Fr;
    Xr[m] = Er - Oi;
    Xi[m] = Ei + Or;
  }
  fft1024(Xr, Xi, sre, sim, twrf, twif, +1.0f);
  float2* frrow = fr2 + row * 1024;
  const float invM = 1.0f / 1024.0f;
#pragma unroll
  for (int m = 0; m < 8; ++m) {          // z[g]: x[2g]=Re, x[2g+1]=Im; coalesced float2
    int g = t + 128 * m;
    float2 w = winp[g];
    frrow[g] = make_float2(Xr[m] * invM * w.x,
                           Xi[m] * invM * w.y);
  }
}

// ---------------- OLA gather + normalize, 4 samples/thread ----------------
__global__ __launch_bounds__(256) void k_ola(const float* __restrict__ fr,
                                             const float* __restrict__ envif,
                                             float* __restrict__ y, float* __restrict__ out) {
  size_t idx = (size_t)blockIdx.x * 256 + threadIdx.x;
  const size_t QROW = LOLA / 4;           // 33280 quads per batch row
  if (idx >= (size_t)BATCH * QROW) return;
  int b = (int)(idx / QROW);
  int i0 = 4 * (int)(idx % QROW);
  const float* frb = fr + (size_t)b * NF * NFFT;
  int lo0 = i0 - (NFFT - 1);
  int fm0 = lo0 <= 0 ? 0 : (lo0 + HOP - 1) / HOP;
  int fx0 = i0 / HOP; if (fx0 > NF - 1) fx0 = NF - 1;
  int i3 = i0 + 3;
  int lo3 = i3 - (NFFT - 1);
  int fm3 = lo3 <= 0 ? 0 : (lo3 + HOP - 1) / HOP;
  int fx3 = i3 / HOP; if (fx3 > NF - 1) fx3 = NF - 1;
  float4 v;
  if (fm0 == fm3 && fx0 == fx3) {         // uniform range: float4 fast path
    float4 s = make_float4(0.f, 0.f, 0.f, 0.f);
    for (int f = fm0; f <= fx0; ++f) {
      const float4 a = *(const float4*)(frb + (size_t)f * NFFT + (i0 - HOP * f));
      s.x += a.x; s.y += a.y; s.z += a.z; s.w += a.w;
    }
    const float4 e = *(const float4*)(envif + i0);
    v = make_float4(s.x * e.x, s.y * e.y, s.z * e.z, s.w * e.w);
  } else {                                // boundary quad: per-element
    float vv[4];
#pragma unroll
    for (int u = 0; u < 4; ++u) {
      int i = i0 + u;
      int lo = i - (NFFT - 1);
      int fmin = lo <= 0 ? 0 : (lo + HOP - 1) / HOP;
      int fmax = i / HOP; if (fmax > NF - 1) fmax = NF - 1;
      float s = 0.0f;
      for (int f = fmin; f <= fmax; ++f)
        s += frb[(size_t)f * NFFT + (i - HOP * f)];
      vv[u] = s * envif[i];
    }
    v = make_float4(vv[0], vv[1], vv[2], vv[3]);
  }
  if (out) {
    int j0 = i0 - NFFT / 2;               // 1024-aligned shift: j0 % 4 == 0
    if (j0 >= 0 && j0 + 3 < TLEN) {
      *(float4*)(out + (size_t)b * TLEN + j0) = v;
    } else {
      const float vv[4] = {v.x, v.y, v.z, v.w};
#pragma unroll
      for (int u = 0; u < 4; ++u) {
        int j = j0 + u;
        if (j >= 0 && j < TLEN) out[(size_t)b * TLEN + j] = vv[u];
      }
    }
  } else {
    *(float4*)(y + (size_t)b * LOLA + i0) = v;
  }
}

// ---------------- STFT of inv (real-packed, f32) + GL angle/momentum update ----------------
// mom==0.0 -> P is not read (ar = rr exactly); writeP==0 -> P store skipped (dead on last iter)
__global__ __launch_bounds__(128) void k_stft_gl(const float* __restrict__ y,
                                                 const float2* __restrict__ winp,
                                                 const float* __restrict__ twrf, const float* __restrict__ twif,
                                                 float2* __restrict__ A, float2* __restrict__ P,
                                                 double mom, int writeP) {
  __shared__ float sre[1160], sim[1160];
  int b = blockIdx.x / NF, tf = blockIdx.x % NF;
  int t = threadIdx.x;
  const float* yb = y + (size_t)b * LOLA;
  if (tf >= 4 && tf <= 508) {            // interior: y index = 256*tf + 2n -> float2
    const float2* yb2 = (const float2*)yb;
#pragma unroll
    for (int s = 0; s < 8; ++s) {
      int n = t + 128 * s;
      float2 v = yb2[128 * tf + n];
      float2 w = winp[n];
      sre[PADF(n)] = v.x * w.x;
      sim[PADF(n)] = v.y * w.y;
    }
  } else {
#pragma unroll
    for (int s = 0; s < 8; ++s) {
      int n = t + 128 * s;
      int j0 = HOP * tf + 2 * n - (NFFT / 2);
      int m0 = j0 < 0 ? -j0 : (j0 >= TLEN ? 2 * TLEN - 2 - j0 : j0);
      int j1 = j0 + 1;
      int m1 = j1 < 0 ? -j1 : (j1 >= TLEN ? 2 * TLEN - 2 - j1 : j1);
      float2 w = winp[n];
      sre[PADF(n)] = yb[NFFT/2 + m0] * w.x;
      sim[PADF(n)] = yb[NFFT/2 + m1] * w.y;
    }
  }
  __syncthreads();
  float Xr[8], Xi[8];
  int rt = (int)(__brev((unsigned)t) >> 25);
  const int r3[8] = {0,4,2,6,1,5,3,7};
#pragma unroll
  for (int m = 0; m < 8; ++m) {
    int p = PADF(rt + 128 * r3[m]);
    Xr[m] = sre[p]; Xi[m] = sim[p];
  }
  fft1024(Xr, Xi, sre, sim, twrf, twif, -1.0f);
  float x1024r = 0.0f;
  r2c_combine(Xr, Xi, sre, sim, twrf, twif, x1024r);
  size_t row = blockIdx.x;
  float2* Arow = A + row * NBINS;
  float2* Prow = P + row * NBINS;
  const bool readP = (mom != 0.0);
#pragma unroll
  for (int m = 0; m < 8; ++m) {
    int k = t + 128 * m;
    double rr = (double)Xr[m], ri = (double)Xi[m];
    double ar = rr, ai = ri;
    if (readP) {                          // wave-uniform branch
      float2 p = Prow[k];
      ar = rr - mom * (double)p.x;
      ai = ri - mom * (double)p.y;
    }
    double mg = sqrt(ar * ar + ai * ai) + 1e-16;
    Arow[k] = make_float2((float)(ar / mg), (float)(ai / mg));
    if (writeP) Prow[k] = make_float2((float)rr, (float)ri);
  }
  if (t == 0) {                           // Nyquist bin (imag exactly 0)
    double ar = (double)x1024r, ai = 0.0;
    if (readP) {
      float2 p = Prow[1024];
      ar = (double)x1024r - mom * (double)p.x;
      ai = -mom * (double)p.y;
    }
    double mg = sqrt(ar * ar + ai * ai) + 1e-16;
    Arow[1024] = make_float2((float)(ar / mg), (float)(ai / mg));
    if (writeP) Prow[1024] = make_float2(x1024r, 0.0f);
  }
}

// ---------------- f0 + loudness (parity-split lags: conflict-free LDS) ----------------
__global__ __launch_bounds__(256) void k_feats(const float* __restrict__ x, double* __restrict__ feats) {
  __shared__ float xe[520], xo[520];      // xo[i] = xe[i+1]
  __shared__ double vals[256];
  __shared__ int vidx[256];
  int b = blockIdx.x / NF, tf = blockIdx.x % NF;
  const float* xb = x + (size_t)b * TLEN;
  int tid = threadIdx.x;
  for (int n = tid; n < FRAMEL; n += 256) {
    int j = HOP * tf + n - (FRAMEL / 2);
    int m = j < 0 ? -j : (j >= TLEN ? 2 * TLEN - 2 - j : j);
    xe[n] = xb[m];
  }
  if (tid < 8) xe[FRAMEL + tid] = 0.0f;
  __syncthreads();
  for (int n = tid; n < 519; n += 256) xo[n] = xe[n + 1];
  if (tid == 0) xo[519] = 0.0f;
  // loudness sum of squares (f64 accum of exact f32 values)
  double ss = 0.0;
  for (int n = tid; n < FRAMEL; n += 256) { double v = (double)xe[n]; ss += v * v; }
  vals[tid] = ss;
  __syncthreads();
  for (int w = 128; w > 0; w >>= 1) {
    if (tid < w) vals[tid] += vals[tid + w];
    __syncthreads();
  }
  double sumsq = vals[0];
  __syncthreads();
  int q   = (tid < 128) ? tid : tid - 128;
  int lag = (tid < 128) ? (32 + 2 * q) : (33 + 2 * q);
  bool active = q < 112;
  double acc = -1e300;
  if (active) {
    acc = 0.0;
    const float2* e2 = (const float2*)xe;
    const float2* s2 = (const float2*)((tid < 128) ? xe : xo);
    int kb = 16 + q;                      // lag>>1 for both parities
    for (int n0 = 0; n0 < FRAMEL - lag; n0 += 8) {
      int h = n0 >> 1;
      float2 a0 = e2[h],    a1 = e2[h+1],    a2 = e2[h+2],    a3 = e2[h+3];
      float2 b0 = s2[h+kb], b1 = s2[h+kb+1], b2 = s2[h+kb+2], b3 = s2[h+kb+3];
      acc += (double)a0.x * (double)b0.x; acc += (double)a0.y * (double)b0.y;
      acc += (double)a1.x * (double)b1.x; acc += (double)a1.y * (double)b1.y;
      acc += (double)a2.x * (double)b2.x; acc += (double)a2.y * (double)b2.y;
      acc += (double)a3.x * (double)b3.x; acc += (double)a3.y * (double)b3.y;
    }
  }
  vals[tid] = acc; vidx[tid] = lag;
  __syncthreads();
  for (int w = 128; w > 0; w >>= 1) {     // first-max argmax tree (lag-order tie-break)
    if (tid < w) {
      double vl = vals[tid], vr = vals[tid + w];
      int il = vidx[tid], ir = vidx[tid + w];
      if (vr > vl || (vr == vl && ir < il)) { vals[tid] = vr; vidx[tid] = ir; }
    }
    __syncthreads();
  }
  if (tid == 0) {
    double period = (double)vidx[0];
    double f0 = (double)SRATE / (period + 1e-8);
    f0 = f0 < 50.0 ? 50.0 : (f0 > 500.0 ? 500.0 : f0);
    double mean = sumsq / (double)FRAMEL;
    double loud = 20.0 * log10(sqrt(mean) + 1e-8);
    feats[(size_t)blockIdx.x * 2 + 0] = f0;
    feats[(size_t)blockIdx.x * 2 + 1] = loud;
  }
}

// ---------------- MLP 2->256->256->64 (elu), 8 rows/block ----------------
__global__ __launch_bounds__(256) void k_mlp(const double* __restrict__ feats,
                                             const float* __restrict__ W1, const float* __restrict__ b1,
                                             const float* __restrict__ W2, const float* __restrict__ b2,
                                             const float* __restrict__ W3, const float* __restrict__ b3,
                                             float* __restrict__ out) {
  __shared__ double h1[MLPR][256];
  __shared__ double h2[MLPR][256];
  __shared__ double fsh[MLPR][2];
  int j = threadIdx.x;
  size_t row0 = (size_t)blockIdx.x * MLPR;
  if (j < MLPR * 2) ((double*)fsh)[j] = feats[row0 * 2 + j];
  __syncthreads();
  double w1a = (double)W1[j], w1b = (double)W1[256 + j], bb1 = (double)b1[j];
#pragma unroll
  for (int r = 0; r < MLPR; ++r) {
    double v = fsh[r][0] * w1a + fsh[r][1] * w1b + bb1;
    h1[r][j] = v > 0.0 ? v : expm1(v);
  }
  __syncthreads();
  double acc[MLPR];
  double bb2 = (double)b2[j];
#pragma unroll
  for (int r = 0; r < MLPR; ++r) acc[r] = bb2;
  for (int i = 0; i < 256; ++i) {
    double w = (double)W2[i * 256 + j];
#pragma unroll
    for (int r = 0; r < MLPR; ++r) acc[r] += h1[r][i] * w;
  }
#pragma unroll
  for (int r = 0; r < MLPR; ++r) h2[r][j] = acc[r] > 0.0 ? acc[r] : expm1(acc[r]);
  __syncthreads();
  int o = j & 63, rg = j >> 6;            // 4 row-pairs across 256 threads
  int r0 = rg * 2, r1 = r0 + 1;
  double o0 = (double)b3[o], o1 = o0;
  for (int i = 0; i < 256; ++i) {
    double w = (double)W3[i * 64 + o];
    o0 += h2[r0][i] * w;
    o1 += h2[r1][i] * w;
  }
  out[(row0 + r0) * 64 + o] = (float)o0;
  out[(row0 + r1) * 64 + o] = (float)o1;
}

// sentinel: marks "workspace too small" path unambiguously
__global__ void k_sentinel(float* out) { out[0] = 31337.0f; }

// ---------------- host ----------------
extern "C" void kernel_launch(void* const* d_in, const int* in_sizes, int n_in,
                              void* d_out, int out_size, void* d_ws, size_t ws_size,
                              hipStream_t stream) {
  const float* x  = (const float*)d_in[0];
  const float* W1 = (const float*)d_in[1];
  const float* b1 = (const float*)d_in[2];
  const float* W2 = (const float*)d_in[3];
  const float* b2 = (const float*)d_in[4];
  const float* W3 = (const float*)d_in[5];
  const float* b3 = (const float*)d_in[6];
  float* out = (float*)d_out;

  // f64 region
  double* ws = (double*)d_ws;
  size_t o = 0;
  double*  winsq = ws + o; o += NFFT;
  double*  feats = ws + o; o += (size_t)BATCH * NF * 2;
  // f32 region (8B aligned: o doubles consumed)
  float2* winp  = (float2*)(ws + o);                         // 1024 float2
  float*  twrf  = (float*)(winp + 1024);                     // 1024
  float*  twif  = twrf + 1024;                               // 1024
  float*  fptsf = twif + 1024;                               // 84 (pad to even)
  int2*   melrange = (int2*)(fptsf + 84);                    // 80 int2 (8B aligned)
  float*  mel   = (float*)(melrange + NMELS);                // B*NF*80
  float*  fr    = mel + (size_t)BATCH * NF * NMELS;          // B*NF*2048 windowed frames (16B-aligned rows)
  float*  y     = fr + (size_t)BATCH * NF * NFFT;            // B*LOLA normalized inv
  float*  envif = y + (size_t)BATCH * LOLA;                  // LOLA
  float2* A     = (float2*)(envif + LOLA);
  float2* P     = A + (size_t)NELEM;
  size_t total_bytes = (size_t)((char*)(P + (size_t)NELEM) - (char*)d_ws);  // ~215 MiB

  if (ws_size < total_bytes) {           // diagnostic path: out[0] = 31337
    k_sentinel<<<1, 1, 0, stream>>>(out);
    return;
  }

  // jax.random.key(42) -> (0,42). Partitionable split: keys[i] = threefry(key, (0, i)).
  uint32_t kr0, kr1, ki0, ki1;
  threefry2x32(0u, 42u, 0u, 0u, kr0, kr1);   // kr = keys[0]
  threefry2x32(0u, 42u, 0u, 1u, ki0, ki1);   // ki = keys[1]

  const int NBLK = BATCH * NF;    // 8208
  const int OLAB = ((size_t)BATCH * (LOLA / 4) + 255) / 256;   // 4 samples/thread
  k_init_a<<<8, 256, 0, stream>>>(winp, winsq, twrf, twif, fptsf, melrange);
  k_init_b<<<(LOLA + 255) / 256, 256, 0, stream>>>(winsq, envif);
  k_stft_mel<<<NBLK, 128, 0, stream>>>(x, winp, twrf, twif, fptsf, melrange, mel);
  k_angles<<<(NELEM + 255) / 256, 256, 0, stream>>>(A, kr0, kr1, ki0, ki1);
  // No P memset: first GL iteration uses mom=0 and skips the P read entirely.

  const double mom = 0.99 / 1.99;
  for (int it = 0; it < 4; ++it) {
    k_istft<<<NBLK, 128, 0, stream>>>(mel, A, winp, twrf, twif, (float2*)fr);
    k_ola<<<OLAB, 256, 0, stream>>>(fr, envif, y, nullptr);
    // it==0: mom=0 (P unread). it==3: P dead afterwards -> writeP=0.
    k_stft_gl<<<NBLK, 128, 0, stream>>>(y, winp, twrf, twif, A, P,
                                        it == 0 ? 0.0 : mom, it < 3 ? 1 : 0);
  }
  k_istft<<<NBLK, 128, 0, stream>>>(mel, A, winp, twrf, twif, (float2*)fr);
  k_ola<<<OLAB, 256, 0, stream>>>(fr, envif, y, out);

  k_feats<<<NBLK, 256, 0, stream>>>(x, feats);
  k_mlp<<<NBLK / MLPR, 256, 0, stream>>>(feats, W1, b1, W2, b2, W3, b3, out + (size_t)BATCH * TLEN);
}